// Round 2
// baseline (1894.060 us; speedup 1.0000x reference)
//
#include <hip/hip_runtime.h>
#include <hip/hip_bf16.h>
#include <stdint.h>

#define B_TOK 8192
#define DD_IN 1024
#define D_HID 4096
#define D_OUT 1024
#define N_EXP 8

typedef __attribute__((ext_vector_type(8))) __bf16 bf16x8;
typedef __attribute__((ext_vector_type(4))) float f32x4;

#define GLDS16(g, l) __builtin_amdgcn_global_load_lds( \
    (__attribute__((address_space(1))) void*)(g), \
    (__attribute__((address_space(3))) void*)(l), 16, 0, 0)

// ---------------- gate: softmax(x @ Wg + bg) over E=8, one wave per row ----
__global__ void gate_kernel(const float* __restrict__ x,
                            const float* __restrict__ Wg,
                            const float* __restrict__ bg,
                            float* __restrict__ gate) {
    int wave = threadIdx.x >> 6;
    int lane = threadIdx.x & 63;
    int row  = blockIdx.x * 4 + wave;
    if (row >= B_TOK) return;
    const float* xr = x + (size_t)row * DD_IN;
    float acc[N_EXP];
#pragma unroll
    for (int e = 0; e < N_EXP; ++e) acc[e] = 0.f;
    for (int k = lane; k < DD_IN; k += 64) {
        float xv = xr[k];
        const float* wgr = Wg + (size_t)k * N_EXP;
#pragma unroll
        for (int e = 0; e < N_EXP; ++e) acc[e] += xv * wgr[e];
    }
#pragma unroll
    for (int e = 0; e < N_EXP; ++e) {
        float v = acc[e];
        for (int off = 32; off; off >>= 1) v += __shfl_xor(v, off);
        acc[e] = v + bg[e];
    }
    float m = acc[0];
#pragma unroll
    for (int e = 1; e < N_EXP; ++e) m = fmaxf(m, acc[e]);
    float s = 0.f;
#pragma unroll
    for (int e = 0; e < N_EXP; ++e) { acc[e] = expf(acc[e] - m); s += acc[e]; }
    float inv = 1.f / s;
    if (lane < N_EXP) gate[(size_t)row * N_EXP + lane] = acc[lane] * inv;
}

// ---------------- f32 -> bf16 (8 elems/thread, vectorized) ----------------
__global__ void cvt_x_kernel(const float* __restrict__ in,
                             __bf16* __restrict__ out, int n8) {
    int i = blockIdx.x * blockDim.x + threadIdx.x;
    if (i >= n8) return;
    const float4* p = (const float4*)in + (size_t)i * 2;
    float4 a = p[0], b = p[1];
    bf16x8 o;
    o[0] = (__bf16)a.x; o[1] = (__bf16)a.y; o[2] = (__bf16)a.z; o[3] = (__bf16)a.w;
    o[4] = (__bf16)b.x; o[5] = (__bf16)b.y; o[6] = (__bf16)b.z; o[7] = (__bf16)b.w;
    *(bf16x8*)(out + (size_t)i * 8) = o;
}

// ---- per-expert transpose+convert: in [E][R][C] f32 -> out [E][C][R] bf16 -
__global__ void transpose_cvt_kernel(const float* __restrict__ in,
                                     __bf16* __restrict__ out, int R, int C) {
    __shared__ __bf16 tile[32][34];
    const float* inp = in + (size_t)blockIdx.z * R * C;
    __bf16* outp = out + (size_t)blockIdx.z * R * C;
    int c0 = blockIdx.x * 32, r0 = blockIdx.y * 32;
    int tx = threadIdx.x & 31, ty = threadIdx.x >> 5;  // ty in [0,8)
#pragma unroll
    for (int i = 0; i < 32; i += 8)
        tile[ty + i][tx] = (__bf16)inp[(size_t)(r0 + ty + i) * C + c0 + tx];
    __syncthreads();
#pragma unroll
    for (int i = 0; i < 32; i += 8)
        outp[(size_t)(c0 + ty + i) * R + r0 + tx] = tile[tx][ty + i];
}

// ---------------- 128x128 tile bf16 MFMA GEMM (m97 structure) --------------
// C[M,N] = A[M,K] * Bt[N,K]^T ; EPI 0: outH = bf16(relu(acc+bias))
//                               EPI 1: outF = (first?0:outF) + g*(acc+bias)
template <int EPI>
__global__ __launch_bounds__(256)
void gemm_kernel(const __bf16* __restrict__ A, const __bf16* __restrict__ Bt,
                 const float* __restrict__ bias, const float* __restrict__ gate8,
                 int first, float* __restrict__ outF, __bf16* __restrict__ outH,
                 int N, int K) {
    __shared__ __bf16 As[128 * 32];
    __shared__ __bf16 Bs[128 * 32];
    const int brow = blockIdx.y * 128;
    const int bcol = blockIdx.x * 128;
    const int t = threadIdx.x;
    const int w = t >> 6, l = t & 63;
    const int wr = w >> 1, wc = w & 1;

    f32x4 acc[4][4];
#pragma unroll
    for (int m = 0; m < 4; ++m)
#pragma unroll
        for (int n = 0; n < 4; ++n) acc[m][n] = (f32x4)0.f;

    // staging: thread covers 8 bf16 (16B); wave w, issue j -> rows w*16+l/4 + j*64
    const int srow = w * 16 + (l >> 2);
    const int scol = (l & 3) * 8;
    const __bf16* gA = A + (size_t)(brow + srow) * K + scol;
    const __bf16* gB = Bt + (size_t)(bcol + srow) * K + scol;
    __bf16* lA = As + w * 512 + l * 8;
    __bf16* lB = Bs + w * 512 + l * 8;

    const int kq = (l >> 4) * 8;
    const int rA = wr * 64 + (l & 15);
    const int rB = wc * 64 + (l & 15);

    const int nk = K / 32;
    for (int kt = 0; kt < nk; ++kt) {
#pragma unroll
        for (int j = 0; j < 2; ++j) {
            GLDS16(gA + (size_t)j * 64 * K, lA + j * 2048);
            GLDS16(gB + (size_t)j * 64 * K, lB + j * 2048);
        }
        gA += 32; gB += 32;
        __syncthreads();   // compiler emits vmcnt(0) drain before barrier

        bf16x8 af[4], bfr[4];
#pragma unroll
        for (int m = 0; m < 4; ++m)
            af[m] = *(const bf16x8*)&As[(rA + m * 16) * 32 + kq];
#pragma unroll
        for (int n = 0; n < 4; ++n)
            bfr[n] = *(const bf16x8*)&Bs[(rB + n * 16) * 32 + kq];
#pragma unroll
        for (int m = 0; m < 4; ++m)
#pragma unroll
            for (int n = 0; n < 4; ++n)
                acc[m][n] = __builtin_amdgcn_mfma_f32_16x16x32_bf16(
                    af[m], bfr[n], acc[m][n], 0, 0, 0);
        __syncthreads();
    }

    // epilogue: C/D mapping col=lane&15, row=(lane>>4)*4+j  [m89/m91 verified]
    const int crow = wr * 64 + (l >> 4) * 4;
    const int ccol = bcol + wc * 64 + (l & 15);
    float bv[4];
#pragma unroll
    for (int n = 0; n < 4; ++n) bv[n] = bias[ccol + n * 16];

    if (EPI == 0) {
#pragma unroll
        for (int m = 0; m < 4; ++m)
#pragma unroll
            for (int j = 0; j < 4; ++j) {
                int row = brow + crow + m * 16 + j;
                size_t base = (size_t)row * N + ccol;
#pragma unroll
                for (int n = 0; n < 4; ++n) {
                    float v = acc[m][n][j] + bv[n];
                    outH[base + n * 16] = (__bf16)fmaxf(v, 0.f);
                }
            }
    } else {
#pragma unroll
        for (int m = 0; m < 4; ++m)
#pragma unroll
            for (int j = 0; j < 4; ++j) {
                int row = brow + crow + m * 16 + j;
                float g = gate8[(size_t)row * N_EXP];
                size_t base = (size_t)row * N + ccol;
#pragma unroll
                for (int n = 0; n < 4; ++n) {
                    size_t idx = base + n * 16;
                    float prev = first ? 0.f : outF[idx];
                    outF[idx] = prev + g * (acc[m][n][j] + bv[n]);
                }
            }
    }
}

// ---------------------------------------------------------------------------
extern "C" void kernel_launch(void* const* d_in, const int* in_sizes, int n_in,
                              void* d_out, int out_size, void* d_ws, size_t ws_size,
                              hipStream_t stream) {
    const float* x  = (const float*)d_in[0];
    const float* W1 = (const float*)d_in[1];
    const float* b1 = (const float*)d_in[2];
    const float* W2 = (const float*)d_in[3];
    const float* b2 = (const float*)d_in[4];
    const float* Wg = (const float*)d_in[5];
    const float* bg = (const float*)d_in[6];
    float* out = (float*)d_out;

    char* ws = (char*)d_ws;
    size_t off = 0;
    auto take = [&](size_t bytes) {
        char* p = ws + off;
        off = (off + bytes + 255) & ~(size_t)255;
        return p;
    };
    float*  gate = (float*)take((size_t)B_TOK * N_EXP * 4);
    __bf16* xb   = (__bf16*)take((size_t)B_TOK * DD_IN * 2);
    __bf16* W1t  = (__bf16*)take((size_t)N_EXP * DD_IN * D_HID * 2);
    __bf16* W2t  = (__bf16*)take((size_t)N_EXP * D_HID * D_OUT * 2);
    size_t remain = (ws_size > off) ? (ws_size - off) : 0;
    long chunk = (long)(remain / ((size_t)D_HID * 2));
    chunk &= ~127L;
    if (chunk > B_TOK) chunk = B_TOK;
    if (chunk < 128) chunk = 128;  // below this ws is unusable anyway
    __bf16* h = (__bf16*)(ws + off);

    gate_kernel<<<dim3(B_TOK / 4), dim3(256), 0, stream>>>(x, Wg, bg, gate);

    int n8 = B_TOK * DD_IN / 8;
    cvt_x_kernel<<<dim3(n8 / 256), dim3(256), 0, stream>>>(x, xb, n8);

    transpose_cvt_kernel<<<dim3(D_HID / 32, DD_IN / 32, N_EXP), dim3(256), 0, stream>>>(
        W1, W1t, DD_IN, D_HID);
    transpose_cvt_kernel<<<dim3(D_OUT / 32, D_HID / 32, N_EXP), dim3(256), 0, stream>>>(
        W2, W2t, D_HID, D_OUT);

    for (int e = 0; e < N_EXP; ++e) {
        for (long r0 = 0; r0 < B_TOK; r0 += chunk) {
            long rows = B_TOK - r0;
            if (rows > chunk) rows = chunk;
            gemm_kernel<0><<<dim3(D_HID / 128, rows / 128), dim3(256), 0, stream>>>(
                xb + (size_t)r0 * DD_IN,
                W1t + (size_t)e * DD_IN * D_HID,
                b1 + (size_t)e * D_HID,
                nullptr, 0, nullptr, h, D_HID, DD_IN);
            gemm_kernel<1><<<dim3(D_OUT / 128, rows / 128), dim3(256), 0, stream>>>(
                h,
                W2t + (size_t)e * D_HID * D_OUT,
                b2 + (size_t)e * D_OUT,
                gate + (size_t)r0 * N_EXP + e, (e == 0),
                out + (size_t)r0 * D_OUT, nullptr, D_OUT, D_HID);
        }
    }
}